// Round 13
// baseline (239.272 us; speedup 1.0000x reference)
//
#include <hip/hip_runtime.h>
#include <hip/hip_bf16.h>
#include <math.h>

#define IN_CH 128

typedef __attribute__((ext_vector_type(8))) short bf16x8;
typedef __attribute__((ext_vector_type(4))) float f32x4;

__device__ __forceinline__ ushort f2b(float f) {
    union { float f; uint u; } c; c.f = f;
    uint u = c.u + 0x7fff + ((c.u >> 16) & 1);   // RNE
    return (ushort)(u >> 16);
}
__device__ __forceinline__ float b2f(uint hi16) {
    union { uint u; float f; } c; c.u = hi16 << 16;
    return c.f;
}

// ---------------- fused prep: x->bf16, 4 weight transposes, edge histogram ----------------
// degI/flags zeroed beforehand via hipMemsetAsync (avoids zero-vs-atomic race).
__global__ __launch_bounds__(256) void prep_hist(const float* __restrict__ x,
                                                 ushort* __restrict__ xb, int n8,
                                                 const float* __restrict__ Wl1,
                                                 const float* __restrict__ Wr1,
                                                 const float* __restrict__ Wl2,
                                                 const float* __restrict__ Wr2,
                                                 ushort* __restrict__ WlT1,
                                                 ushort* __restrict__ WrT1,
                                                 ushort* __restrict__ WlT2,
                                                 ushort* __restrict__ WrT2,
                                                 const int* __restrict__ edst,
                                                 int* __restrict__ degI,
                                                 int* __restrict__ rank, int nE) {
    int i = blockIdx.x * 256 + threadIdx.x;
    if (i < nE) rank[i] = atomicAdd(&degI[edst[i]], 1);
    if (i < n8) {
        float4 a = ((const float4*)x)[2 * i];
        float4 b = ((const float4*)x)[2 * i + 1];
        union { ushort u[8]; uint4 v; } p;
        p.u[0] = f2b(a.x); p.u[1] = f2b(a.y); p.u[2] = f2b(a.z); p.u[3] = f2b(a.w);
        p.u[4] = f2b(b.x); p.u[5] = f2b(b.y); p.u[6] = f2b(b.z); p.u[7] = f2b(b.w);
        ((uint4*)xb)[i] = p.v;
    } else {
        int w = i - n8;
        if (w < 2 * 16384 + 2 * 8192) {
            const float* W; ushort* Wt; int N, r;
            if (w < 16384)      { W = Wl1; Wt = WlT1; N = 128; r = w; }
            else if (w < 32768) { W = Wr1; Wt = WrT1; N = 128; r = w - 16384; }
            else if (w < 40960) { W = Wl2; Wt = WlT2; N = 64;  r = w - 32768; }
            else                { W = Wr2; Wt = WrT2; N = 64;  r = w - 40960; }
            int n = r / 128, k = r % 128;
            Wt[n * 128 + k] = f2b(W[(size_t)k * N + n]);
        }
    }
}

// ---------------- single-pass exclusive scan (49 blocks, co-resident publish+spin) ----------------
__global__ __launch_bounds__(256) void scan_fused(const int* __restrict__ deg,
                                                  int* __restrict__ bsum,
                                                  int* __restrict__ flags,
                                                  int* __restrict__ row_ptr,
                                                  int n, int nE) {
    const int tid = threadIdx.x, lane = tid & 63, wid = tid >> 6;
    const int base = blockIdx.x * 1024 + tid * 4;
    int v[4];
    int tsum = 0;
    #pragma unroll
    for (int k = 0; k < 4; ++k) {
        int idx = base + k;
        v[k] = (idx < n) ? deg[idx] : 0;
        tsum += v[k];
    }
    int incl = tsum;
    #pragma unroll
    for (int off = 1; off < 64; off <<= 1) {
        int t = __shfl_up(incl, off);
        if (lane >= off) incl += t;
    }
    __shared__ int ws[4];
    if (lane == 63) ws[wid] = incl;
    __syncthreads();
    if (tid == 0) {
        int btot = ws[0] + ws[1] + ws[2] + ws[3];
        __hip_atomic_store(&bsum[blockIdx.x], btot, __ATOMIC_RELAXED, __HIP_MEMORY_SCOPE_AGENT);
        __hip_atomic_store(&flags[blockIdx.x], 1, __ATOMIC_RELEASE, __HIP_MEMORY_SCOPE_AGENT);
    }
    __shared__ int s_off;
    if (tid < 64) {
        int contrib = 0;
        if (tid < blockIdx.x) {            // gridDim <= 64
            while (!__hip_atomic_load(&flags[tid], __ATOMIC_ACQUIRE, __HIP_MEMORY_SCOPE_AGENT))
                __builtin_amdgcn_s_sleep(1);
            contrib = __hip_atomic_load(&bsum[tid], __ATOMIC_RELAXED, __HIP_MEMORY_SCOPE_AGENT);
        }
        #pragma unroll
        for (int off = 32; off >= 1; off >>= 1) contrib += __shfl_xor(contrib, off);
        if (tid == 0) s_off = contrib;
    }
    if (blockIdx.x == 0 && tid == 0) row_ptr[n] = nE;
    __syncthreads();
    int woff = 0;
    #pragma unroll
    for (int w = 0; w < 4; ++w) woff += (w < wid) ? ws[w] : 0;
    int off = s_off + woff + (incl - tsum);
    #pragma unroll
    for (int k = 0; k < 4; ++k) {
        int idx = base + k;
        if (idx < n) row_ptr[idx] = off;
        off += v[k];
    }
}

// ---------------- scatter edges into CSR (no atomics; rank precomputed) ----------------
__global__ __launch_bounds__(256) void scatter_edges(const int* __restrict__ src,
                                                     const int* __restrict__ dst,
                                                     const int* __restrict__ row_ptr,
                                                     const int* __restrict__ rank,
                                                     int* __restrict__ ssrc, int nE) {
    int i = blockIdx.x * 256 + threadIdx.x;
    if (i < nE) {
        int d = dst[i];
        ssrc[row_ptr[d] + rank[i]] = src[i];
    }
}

// ---------------- mean aggregation (layer 1): one wave per node, uniform idx-prefetch ----------------
__global__ __launch_bounds__(256) void agg_mean(const ushort* __restrict__ feat,
                                                const int* __restrict__ row_ptr,
                                                const int* __restrict__ ssrc,
                                                ushort* __restrict__ out, int nNodes) {
    const int node = blockIdx.x * 4 + (threadIdx.x >> 6);
    const int lane = threadIdx.x & 63;
    if (node >= nNodes) return;
    const int q = lane >> 4, rr = lane & 15;
    const int beg = row_ptr[node];
    const int deg = row_ptr[node + 1] - beg;   // wave-uniform

    float a[8];
    #pragma unroll
    for (int e = 0; e < 8; ++e) a[e] = 0.f;

    const ushort* fb = feat + rr * 8;
    int idx = 0;
    if (lane < deg) idx = ssrc[beg + lane];
    const int nf8 = min(deg, 64) & ~7;         // wave-uniform, multiple of 8

    int j = 0;
    for (; j < nf8; j += 8) {                  // uniform execution: shfl safe
        int s0 = __shfl(idx, j + q);
        int s1 = __shfl(idx, j + 4 + q);
        bf16x8 v0 = *(const bf16x8*)(fb + (size_t)s0 * IN_CH);
        bf16x8 v1 = *(const bf16x8*)(fb + (size_t)s1 * IN_CH);
        #pragma unroll
        for (int e = 0; e < 8; ++e) a[e] += b2f((ushort)v0[e]);
        #pragma unroll
        for (int e = 0; e < 8; ++e) a[e] += b2f((ushort)v1[e]);
    }
    for (; j < deg; j += 4) {                  // tail: direct loads, no shfl
        if (j + q < deg) {
            int s = ssrc[beg + j + q];
            bf16x8 v = *(const bf16x8*)(fb + (size_t)s * IN_CH);
            #pragma unroll
            for (int e = 0; e < 8; ++e) a[e] += b2f((ushort)v[e]);
        }
    }

    #pragma unroll
    for (int e = 0; e < 8; ++e) {
        a[e] += __shfl_xor(a[e], 16);
        a[e] += __shfl_xor(a[e], 32);
    }

    if (q == 0) {
        float inv = 1.0f / fmaxf((float)deg, 1.0f);
        union { ushort u[8]; uint4 v; } p;
        #pragma unroll
        for (int e = 0; e < 8; ++e) p.u[e] = f2b(a[e] * inv);
        ((uint4*)(out + (size_t)node * IN_CH))[rr] = p.v;
    }
}

// ---------------- fused layers 1+2 GEMM, COLUMN-SPLIT across 8 waves ----------------
// Block = 16 rows, 512 threads (8 waves). Phase 1: wave w computes h columns
// w*16..w*16+15 (8 MFMA), deposits to shared LDS h-tile [16][136]. Sync.
// Phase 2: waves 0-3 compute y2 col-tiles, waves 4-7 compute s2 col-tiles
// (4 MFMA each). 25000 short waves -> latency hidden by TLP.
__global__ __launch_bounds__(512) void gemm_l12(const ushort* __restrict__ A,
                                                const ushort* __restrict__ B,
                                                const ushort* __restrict__ WlT1,
                                                const ushort* __restrict__ WrT1,
                                                const float* __restrict__ bl1,
                                                const ushort* __restrict__ WlT2,
                                                const ushort* __restrict__ WrT2,
                                                ushort* __restrict__ y2,
                                                float* __restrict__ s2, int nRows) {
    constexpr int HS = 136;                    // padded row stride (bf16 elems)
    __shared__ ushort hs[16][HS];

    const int lane = threadIdx.x & 63;
    const int w = threadIdx.x >> 6;            // 0..7
    const int m0 = blockIdx.x * 16;
    const int r = lane & 15, g = lane >> 4;
    int row = m0 + r;
    if (row >= nRows) row = nRows - 1;         // clamp loads; stores masked
    const int kc = g * 8;

    // ---- phase 1: wave w computes h[:, w*16 .. w*16+15] ----
    f32x4 acc = (f32x4){0.f, 0.f, 0.f, 0.f};
    {
        const ushort* wrow1 = WlT1 + (size_t)(w * 16 + r) * 128 + kc;
        const ushort* wrow2 = WrT1 + (size_t)(w * 16 + r) * 128 + kc;
        const ushort* arow = A + (size_t)row * 128 + kc;
        const ushort* brow = B + (size_t)row * 128 + kc;
        #pragma unroll
        for (int k0 = 0; k0 < 128; k0 += 32) {
            bf16x8 af = *(const bf16x8*)(arow + k0);
            bf16x8 wv = *(const bf16x8*)(wrow1 + k0);
            acc = __builtin_amdgcn_mfma_f32_16x16x32_bf16(af, wv, acc, 0, 0, 0);
        }
        #pragma unroll
        for (int k0 = 0; k0 < 128; k0 += 32) {
            bf16x8 bf = *(const bf16x8*)(brow + k0);
            bf16x8 wv = *(const bf16x8*)(wrow2 + k0);
            acc = __builtin_amdgcn_mfma_f32_16x16x32_bf16(bf, wv, acc, 0, 0, 0);
        }
    }
    {
        float bv = bl1[w * 16 + r];
        #pragma unroll
        for (int q = 0; q < 4; ++q) {
            float v = fmaxf(acc[q] + bv, 0.f);
            hs[g * 4 + q][w * 16 + r] = f2b(v);
        }
    }
    __syncthreads();

    // ---- phase 2: waves 0-3 -> y2 tile w; waves 4-7 -> s2 tile w-4 ----
    const int t = w & 3;
    const ushort* Wt2 = (w < 4) ? WlT2 : WrT2;
    f32x4 acc2 = (f32x4){0.f, 0.f, 0.f, 0.f};
    #pragma unroll
    for (int c = 0; c < 4; ++c) {
        bf16x8 af = *(const bf16x8*)(&hs[r][c * 32 + kc]);
        bf16x8 wv = *(const bf16x8*)(Wt2 + (size_t)(t * 16 + r) * 128 + c * 32 + kc);
        acc2 = __builtin_amdgcn_mfma_f32_16x16x32_bf16(af, wv, acc2, 0, 0, 0);
    }

    const int rbase = m0 + g * 4;
    if (w < 4) {
        #pragma unroll
        for (int q = 0; q < 4; ++q)
            if (rbase + q < nRows)
                y2[(size_t)(rbase + q) * 64 + t * 16 + r] = f2b(acc2[q]);
    } else {
        #pragma unroll
        for (int q = 0; q < 4; ++q)
            if (rbase + q < nRows)
                s2[(size_t)(rbase + q) * 64 + t * 16 + r] = acc2[q];
    }
}

// ---------------- layer-2 final: out = log_softmax(mean_agg(y2) + s2 + bias) ----------------
__global__ __launch_bounds__(256) void agg_final(const ushort* __restrict__ y2,
                                                 const float* __restrict__ s2,
                                                 const int* __restrict__ row_ptr,
                                                 const int* __restrict__ ssrc,
                                                 const float* __restrict__ bias,
                                                 float* __restrict__ out, int nNodes) {
    const int node = blockIdx.x * 4 + (threadIdx.x >> 6);
    const int lane = threadIdx.x & 63;
    if (node >= nNodes) return;
    const int q = lane >> 4, rr = lane & 15;
    const int beg = row_ptr[node];
    const int deg = row_ptr[node + 1] - beg;   // wave-uniform

    float a[4] = {0.f, 0.f, 0.f, 0.f};
    const ushort* yb = y2 + rr * 4;
    int idx = 0;
    if (lane < deg) idx = ssrc[beg + lane];
    const int nf8 = min(deg, 64) & ~7;         // wave-uniform, multiple of 8

    #define ACC(vv) { a[0] += b2f((vv).x & 0xffffu); a[1] += b2f((vv).x >> 16); \
                      a[2] += b2f((vv).y & 0xffffu); a[3] += b2f((vv).y >> 16); }
    int j = 0;
    for (; j < nf8; j += 8) {                  // uniform execution: shfl safe
        int s0 = __shfl(idx, j + q);
        int s1 = __shfl(idx, j + 4 + q);
        uint2 v0 = *(const uint2*)(yb + (size_t)s0 * 64);
        uint2 v1 = *(const uint2*)(yb + (size_t)s1 * 64);
        ACC(v0); ACC(v1);
    }
    for (; j < deg; j += 4) {                  // tail: direct loads, no shfl
        if (j + q < deg) {
            int s = ssrc[beg + j + q];
            uint2 v = *(const uint2*)(yb + (size_t)s * 64);
            ACC(v);
        }
    }
    #undef ACC

    #pragma unroll
    for (int e = 0; e < 4; ++e) {
        a[e] += __shfl_xor(a[e], 16);
        a[e] += __shfl_xor(a[e], 32);
    }

    if (q == 0) {
        float inv = 1.0f / fmaxf((float)deg, 1.0f);
        float4 sv = ((const float4*)(s2 + (size_t)node * 64))[rr];
        float4 bv = ((const float4*)bias)[rr];
        float v0 = a[0] * inv + sv.x + bv.x;
        float v1 = a[1] * inv + sv.y + bv.y;
        float v2 = a[2] * inv + sv.z + bv.z;
        float v3 = a[3] * inv + sv.w + bv.w;
        float m = fmaxf(fmaxf(v0, v1), fmaxf(v2, v3));
        #pragma unroll
        for (int off = 8; off >= 1; off >>= 1) m = fmaxf(m, __shfl_xor(m, off));
        float s = expf(v0 - m) + expf(v1 - m) + expf(v2 - m) + expf(v3 - m);
        #pragma unroll
        for (int off = 8; off >= 1; off >>= 1) s += __shfl_xor(s, off);
        float lse = m + logf(s);
        float4 o = {v0 - lse, v1 - lse, v2 - lse, v3 - lse};
        ((float4*)(out + (size_t)node * 64))[rr] = o;
    }
}

extern "C" void kernel_launch(void* const* d_in, const int* in_sizes, int n_in,
                              void* d_out, int out_size, void* d_ws, size_t ws_size,
                              hipStream_t stream) {
    const float* x   = (const float*)d_in[0];
    const int* edges = (const int*)d_in[1];
    const float* Wl1 = (const float*)d_in[2];
    const float* bl1 = (const float*)d_in[3];
    const float* Wr1 = (const float*)d_in[4];
    const float* Wl2 = (const float*)d_in[5];
    const float* bl2 = (const float*)d_in[6];
    const float* Wr2 = (const float*)d_in[7];
    float* out = (float*)d_out;

    const int nN = in_sizes[0] / IN_CH;   // 50000
    const int nE = in_sizes[1] / 2;       // 600000

    // workspace carve
    ushort* xb   = (ushort*)d_ws;                 // nN*128 bf16
    ushort* aggb = xb + (size_t)nN * IN_CH;       // nN*128 bf16 (layer-1 agg)
    ushort* y2   = aggb + (size_t)nN * IN_CH;     // nN*64 bf16
    float*  s2   = (float*)(y2 + (size_t)nN * 64);// nN*64 f32
    ushort* WlT1 = (ushort*)(s2 + (size_t)nN * 64); // 128*128
    ushort* WrT1 = WlT1 + 128 * 128;              // 128*128
    ushort* WlT2 = WrT1 + 128 * 128;              // 64*128
    ushort* WrT2 = WlT2 + 64 * 128;               // 64*128
    int* degI    = (int*)(WrT2 + 64 * 128);       // nN
    int* flags   = degI + nN;                     // 64 (zeroed with degI)
    int* row_ptr = flags + 64;                    // nN+1
    int* bsum    = row_ptr + (nN + 1);            // <=64
    int* ssrc    = bsum + 64;                     // nE
    int* rank    = ssrc + nE;                     // nE

    const int* esrc = edges;
    const int* edst = edges + nE;

    const int n8 = nN * IN_CH / 8;                // 800000
    const int nb = (nN + 1023) / 1024;            // 49 (<=64 required)
    const int nwork = (n8 + 49152 > nE) ? n8 + 49152 : nE;

    hipMemsetAsync(degI, 0, sizeof(int) * (size_t)(nN + 64), stream);  // degI + flags

    prep_hist<<<(nwork + 255) / 256, 256, 0, stream>>>(x, xb, n8,
                                                       Wl1, Wr1, Wl2, Wr2,
                                                       WlT1, WrT1, WlT2, WrT2,
                                                       edst, degI, rank, nE);

    scan_fused<<<nb, 256, 0, stream>>>(degI, bsum, flags, row_ptr, nN, nE);
    scatter_edges<<<(nE + 255) / 256, 256, 0, stream>>>(esrc, edst, row_ptr, rank, ssrc, nE);

    // layer 1 gather
    agg_mean<<<(nN + 3) / 4, 256, 0, stream>>>(xb, row_ptr, ssrc, aggb, nN);

    // fused layer-1 GEMM + layer-2 transform (h stays in LDS), column-split waves
    gemm_l12<<<(nN + 15) / 16, 512, 0, stream>>>(aggb, xb, WlT1, WrT1, bl1,
                                                 WlT2, WrT2, y2, s2, nN);

    // layer-2 gather + epilogue
    agg_final<<<(nN + 3) / 4, 256, 0, stream>>>(y2, s2, row_ptr, ssrc, bl2, out, nN);
}